// Round 4
// baseline (154.523 us; speedup 1.0000x reference)
//
#include <hip/hip_runtime.h>

// soft max-pool 2x2/s2 via composed polynomial sign approximation.
// x: (32, 64, 112, 112) f32  ->  out: (32, 64, 56, 56) f32
// Memory-bound target: 102.8 MB read + 25.7 MB write -> ~20.4 us @ 6.3 TB/s.
//
// R3 change (rerun; R3 bench failed on GPU acquisition, kernel never ran):
// DENSE load instructions. Previous variants had per-lane 16B loads at 32B
// lane stride (each thread took 8 consecutive floats) -> every load
// instruction touched 2x the cache lines of a dense one; L1/TCP pays per
// line per instruction -> load path at ~50% efficiency (~33us observed vs
// 20us roofline; store shape & occupancy already exonerated in R2).
// Now: one thread = one f4 per input row = 2 output cols. Consecutive lanes
// load consecutive 16B (fully dense); the 2x2 windows are lane-local
// (pairs (x,y),(z,w) horizontal, row-pair vertical) -> no shuffle, no LDS.
// Store = 8B/lane, lane-consecutive (dense). Threads double to 3.2M.
//
// R1 finding: nontemporal hints neutral. R2 finding: store shape/occupancy
// neutral.
//
// Overflow handling: with the test's random coeffs the composed polys blow up.
// Bound analysis (|c_k| <= 8, inputs p in (0.05,0.95)):
//   leaf maxes: |d|<=0.9 -> |poly1|<=46 -> |s|<=4e12 -> |out|<=1.8e12 (clamp-free)
//   root max: clamp d to 1e4 and inter-stage y to 1e4; use CLAMPED d in the
//   product -> |out| <= ~4e32. Everything finite, no inf, no NaN.
//   In the normal regime (|values| < 1e4) this is bit-identical to reference.

#define W_IN 112
#define W_OUT 56
#define CH_IN_STRIDE (112 * 112)   // 12544
#define CH_OUT_STRIDE (56 * 56)    // 3136

typedef float f4 __attribute__((ext_vector_type(4)));
typedef float f2 __attribute__((ext_vector_type(2)));

constexpr float SF     = 0.499755859375f;      // (1 - 4*0.5^13)/2 = 2047/4096
constexpr float INV_SF = 4096.0f / 2047.0f;    // exact-constant reciprocal
constexpr float DCLAMP = 1.0e4f;

__device__ __forceinline__ float horner(float x, const float c[8]) {
    float acc = c[7];
#pragma unroll
    for (int k = 6; k >= 0; --k) acc = fmaf(acc, x, c[k]);
    return acc;
}

__device__ __forceinline__ float clampd(float x) {
    return fminf(fmaxf(x, -DCLAMP), DCLAMP);   // v_med3_f32
}

// leaf max: inputs in (0,1); provably overflow-free, no clamps.
__device__ __forceinline__ float max_leaf(float a, float b,
                                          const float c0[8], const float c1[8]) {
    float d = a - b;
    float s = horner(horner(d, c0), c1);
    return (a + b + d * s) * 0.5f;
}

// root max: inputs may be huge; clamp d and inter-stage value.
__device__ __forceinline__ float max_root(float a, float b,
                                          const float c0[8], const float c1[8]) {
    float dc = clampd(a - b);
    float s  = horner(clampd(horner(dc, c0)), c1);
    return (a + b + dc * s) * 0.5f;
}

// one 2x2 window -> one output
__device__ __forceinline__ float pool1(float e0, float e1, float e2, float e3,
                                       const float c0[8], const float c1[8]) {
    float p0 = fmaf(e0, SF, 0.5f);
    float p1 = fmaf(e1, SF, 0.5f);
    float p2 = fmaf(e2, SF, 0.5f);
    float p3 = fmaf(e3, SF, 0.5f);
    float s1 = max_leaf(p0, p1, c0, c1);
    float s2 = max_leaf(p2, p3, c0, c1);
    float r  = max_root(s1, s2, c0, c1);
    return (r - 0.5f) * INV_SF;
}

__global__ __launch_bounds__(256) void maxpool_approx_kernel(
    const float* __restrict__ x,
    const float* __restrict__ cc0,
    const float* __restrict__ cc1,
    float* __restrict__ out) {
    int t = blockIdx.x * blockDim.x + threadIdx.x;

    // t -> (nc, r, j): j = f4-chunk index within the row (2 output cols)
    int j    = t % 28;
    int rest = t / 28;
    int r    = rest % 56;
    int nc   = rest / 56;

    // coefficients: uniform address -> scalar loads; keep in regs
    float c0[8], c1[8];
#pragma unroll
    for (int k = 0; k < 8; ++k) { c0[k] = cc0[k]; c1[k] = cc1[k]; }

    // input rows 2r, 2r+1; cols [4*j, 4*j+4). Consecutive lanes ->
    // consecutive 16B addresses: fully dense load instructions.
    const f4* base = (const f4*)(x + (size_t)nc * CH_IN_STRIDE
                                   + (size_t)(2 * r) * W_IN + 4 * j);
    const int rowf4 = W_IN / 4;   // 28 f4 per input row

    f4 a = base[0];        // row 2r
    f4 b = base[rowf4];    // row 2r+1

    f2 res;
    res.x = pool1(a.x, a.y, b.x, b.y, c0, c1);
    res.y = pool1(a.z, a.w, b.z, b.w, c0, c1);

    // out row r, cols [2*j, 2*j+2): 8B/lane, lane-consecutive (dense)
    f2* ob = (f2*)(out + (size_t)nc * CH_OUT_STRIDE + (size_t)r * W_OUT + 2 * j);
    *ob = res;
}

extern "C" void kernel_launch(void* const* d_in, const int* in_sizes, int n_in,
                              void* d_out, int out_size, void* d_ws, size_t ws_size,
                              hipStream_t stream) {
    const float* x   = (const float*)d_in[0];
    const float* cc0 = (const float*)d_in[1];
    const float* cc1 = (const float*)d_in[2];
    float* out = (float*)d_out;

    // 2048 (n*c) * 56 rows * 28 f4-chunks = 3,211,264 threads
    int total = 2048 * 56 * 28;
    int threads = 256;
    int blocks = total / threads;   // 12544
    maxpool_approx_kernel<<<blocks, threads, 0, stream>>>(x, cc0, cc1, out);
}